// Round 1
// baseline (270.744 us; speedup 1.0000x reference)
//
#include <hip/hip_runtime.h>
#include <math.h>

#define NIN  8
#define NOUT 8
#define DIN  64
#define DOUT 64
#define BSZ  32
#define SEQ  512
#define JB   16384
#define FEPS 1e-9f

// ws float offsets (all zero-init region must be within [0, 2048))
#define WS_UMEAN 0      // 512 floats  : sum over batch of u[i][d]  (atomic)
#define WS_BD0   512    // 64 floats   : B-delta of routing iter 0
#define WS_BD1   576    // 64 floats   : B-delta of routing iter 1
#define WS_T0    1024   // 512 floats  : t[j][d] iter 0 (atomic)
#define WS_T1    1536   // 512 floats  : t[j][d] iter 1 (atomic)
#define WS_UHM   2048   // 4096 floats : u_hat_mean stored as [j][i][e]
#define WS_R2    8192   // 131072 floats: r2[row][j], row = b*512+s (x-native)

// ---------------------------------------------------------------- k_mean
// u_mean_sum[i][d] = sum over all (b,s) of x[i][b][s][d]
__global__ __launch_bounds__(256) void k_mean(const float* __restrict__ x,
                                              float* __restrict__ ws) {
  int blk = blockIdx.x;          // 256 blocks: i (8) x chunk (32)
  int i = blk >> 5;
  int c32 = blk & 31;
  int t = threadIdx.x;
  int q = t & 15;                // float4 column 0..15
  int rsub = t >> 4;             // 16 rows in flight
  const float4* xr = reinterpret_cast<const float4*>(x) +
                     (size_t)(i * JB + c32 * 512) * 16;
  float4 a = make_float4(0.f, 0.f, 0.f, 0.f);
  for (int rr = rsub; rr < 512; rr += 16) {
    float4 v = xr[rr * 16 + q];
    a.x += v.x; a.y += v.y; a.z += v.z; a.w += v.w;
  }
  __shared__ float4 s4[256];
  s4[t] = a;
  __syncthreads();
  if (t < 16) {
    float4 s = s4[t];
    for (int k = 1; k < 16; ++k) {
      float4 v = s4[t + k * 16];
      s.x += v.x; s.y += v.y; s.z += v.z; s.w += v.w;
    }
    float* um = ws + WS_UMEAN + i * 64 + q * 4;
    atomicAdd(um + 0, s.x);
    atomicAdd(um + 1, s.y);
    atomicAdd(um + 2, s.z);
    atomicAdd(um + 3, s.w);
  }
}

// ---------------------------------------------------------------- k_uhm
// uhm[j][i][e] = (1/JB) * sum_d weights[i][j][d][e] * u_mean_sum[i][d]
__global__ __launch_bounds__(64) void k_uhm(const float* __restrict__ w,
                                            float* __restrict__ ws) {
  int blk = blockIdx.x;          // 64 blocks: i*8+j
  int i = blk >> 3, j = blk & 7;
  int e = threadIdx.x;
  const float* wij = w + (size_t)((i * 8 + j) * 64) * 64;
  const float* ums = ws + WS_UMEAN + i * 64;
  float acc = 0.f;
  for (int d = 0; d < 64; ++d)
    acc += wij[d * 64 + e] * ums[d];
  ws[WS_UHM + (j * 8 + i) * 64 + e] = acc * (1.0f / (float)JB);
}

// ---------------------------------------------------------------- k_r2
// r2[row][j] = || W7[j]^T u7[row] ||^2  (row in x-native b*512+s order)
__global__ __launch_bounds__(256) void k_r2(const float* __restrict__ x,
                                            const float* __restrict__ w,
                                            float* __restrict__ ws) {
  __shared__ float ut[32][65];   // +1 pad: conflict-free column reads
  int t = threadIdx.x;
  int row0 = blockIdx.x * 32;    // 512 blocks
  const float* x7 = x + (size_t)7 * JB * 64;
  for (int k = 0; k < 8; ++k) {
    int flat = t + k * 256;      // 0..2047, coalesced
    ut[flat >> 6][flat & 63] = x7[(size_t)row0 * 64 + flat];
  }
  __syncthreads();
  int bl = t & 31, j = t >> 5;
  const float* w7j = w + (size_t)((7 * 8 + j) * 64) * 64;
  float acc[64];
  #pragma unroll
  for (int e = 0; e < 64; ++e) acc[e] = 0.f;
  for (int d = 0; d < 64; ++d) {
    float ud = ut[bl][d];        // broadcast within half-wave, no conflicts
    const float4* w4 = reinterpret_cast<const float4*>(w7j + d * 64);
    #pragma unroll
    for (int eq = 0; eq < 16; ++eq) {
      float4 wv = w4[eq];        // uniform per j -> L1/L2 broadcast
      acc[eq * 4 + 0] += wv.x * ud;
      acc[eq * 4 + 1] += wv.y * ud;
      acc[eq * 4 + 2] += wv.z * ud;
      acc[eq * 4 + 3] += wv.w * ud;
    }
  }
  float r2 = 0.f;
  #pragma unroll
  for (int e = 0; e < 64; ++e) r2 += acc[e] * acc[e];
  ws[WS_R2 + (size_t)(row0 + bl) * 8 + j] = r2;
}

// ---------------------------------------------------------------- k_t
// t[j][d] += sum over rows of g(c_j, r2[row][j]) * u7[row][d]
// bsrc == nullptr  -> iteration 0, C[7][j] = 1/8 exactly (softmax of zeros)
__global__ __launch_bounds__(256) void k_t(const float* __restrict__ x,
                                           const float* __restrict__ ws,
                                           const float* __restrict__ bsrc,
                                           float* __restrict__ tdst) {
  __shared__ float ut[64][65];
  __shared__ float gl[64][8];
  __shared__ float cl[8];
  int t = threadIdx.x;
  if (t < 8) {
    float c;
    if (bsrc == nullptr) {
      c = 0.125f;
    } else {
      float bv[8]; float m = -1e30f;
      for (int i = 0; i < 8; ++i) { bv[i] = bsrc[i * 8 + t]; m = fmaxf(m, bv[i]); }
      float s = 0.f;
      for (int i = 0; i < 8; ++i) s += expf(bv[i] - m);
      c = expf(bv[7] - m) / s;
    }
    cl[t] = c;
  }
  __syncthreads();
  int j = t >> 5, dp = t & 31;
  float a0 = 0.f, a1 = 0.f;
  const float* x7 = x + (size_t)7 * JB * 64;
  const float* r2p = ws + WS_R2;
  int rowbase0 = blockIdx.x * 256;   // 64 blocks x 256 rows
  for (int st = 0; st < 4; ++st) {
    int rowbase = rowbase0 + st * 64;
    for (int k = 0; k < 16; ++k) {
      int flat = t + k * 256;        // 0..4095
      ut[flat >> 6][flat & 63] = x7[(size_t)rowbase * 64 + flat];
    }
    for (int k = 0; k < 2; ++k) {
      int idx = t + k * 256;         // 0..511
      int r = idx >> 3, jj = idx & 7;
      float r2v = r2p[(size_t)(rowbase + r) * 8 + jj];
      float c = cl[jj];
      float s2 = c * c * r2v;
      gl[r][jj] = c * s2 / ((1.f + s2) * sqrtf(s2 + FEPS));
    }
    __syncthreads();
    for (int r = 0; r < 64; ++r) {
      float g = gl[r][j];            // broadcast
      a0 += g * ut[r][2 * dp];       // 2-way bank alias: free on gfx950
      a1 += g * ut[r][2 * dp + 1];
    }
    __syncthreads();
  }
  atomicAdd(&tdst[j * 64 + 2 * dp], a0);
  atomicAdd(&tdst[j * 64 + 2 * dp + 1], a1);
}

// ---------------------------------------------------------------- k_bup
// v_mean[j][e] = (1/JB) sum_d W7[j][d][e] * t[j][d]
// bdst[i][j]   = sum_e uhm[j][i][e] * v_mean[j][e]
__global__ __launch_bounds__(512) void k_bup(const float* __restrict__ w,
                                             const float* __restrict__ ws,
                                             const float* __restrict__ tsrc,
                                             float* __restrict__ bdst) {
  __shared__ float vm[8][64];
  int t = threadIdx.x;               // 512
  int j = t >> 6, e = t & 63;
  const float* w7j = w + (size_t)((7 * 8 + j) * 64) * 64;
  const float* tj = tsrc + j * 64;
  float acc = 0.f;
  for (int d = 0; d < 64; ++d)
    acc += w7j[d * 64 + e] * tj[d];
  vm[j][e] = acc * (1.0f / (float)JB);
  __syncthreads();
  if (t < 64) {
    int i = t >> 3, jj = t & 7;
    const float* uhm = ws + WS_UHM + (jj * 8 + i) * 64;
    float b = 0.f;
    for (int ee = 0; ee < 64; ++ee)
      b += uhm[ee] * vm[jj][ee];
    bdst[i * 8 + jj] = b;
  }
}

// ---------------------------------------------------------------- k_final
// out[j][R] = g(c_final_j, r2) * (W7[j]^T u7[row]),  R = s*32+b remap
__global__ __launch_bounds__(256) void k_final(const float* __restrict__ x,
                                               const float* __restrict__ w,
                                               const float* __restrict__ ws,
                                               float* __restrict__ out) {
  __shared__ float ut[32][65];
  __shared__ float cl[8];
  int t = threadIdx.x;
  if (t < 8) {
    float bv[8]; float m = -1e30f;
    for (int i = 0; i < 8; ++i) {
      bv[i] = ws[WS_BD0 + i * 8 + t] + ws[WS_BD1 + i * 8 + t];
      m = fmaxf(m, bv[i]);
    }
    float s = 0.f;
    for (int i = 0; i < 8; ++i) s += expf(bv[i] - m);
    cl[t] = expf(bv[7] - m) / s;
  }
  int row0 = blockIdx.x * 32;        // 512 blocks
  const float* x7 = x + (size_t)7 * JB * 64;
  for (int k = 0; k < 8; ++k) {
    int flat = t + k * 256;
    ut[flat >> 6][flat & 63] = x7[(size_t)row0 * 64 + flat];
  }
  __syncthreads();
  int bl = t & 31, j = t >> 5;
  const float* w7j = w + (size_t)((7 * 8 + j) * 64) * 64;
  float acc[64];
  #pragma unroll
  for (int e = 0; e < 64; ++e) acc[e] = 0.f;
  for (int d = 0; d < 64; ++d) {
    float ud = ut[bl][d];
    const float4* w4 = reinterpret_cast<const float4*>(w7j + d * 64);
    #pragma unroll
    for (int eq = 0; eq < 16; ++eq) {
      float4 wv = w4[eq];
      acc[eq * 4 + 0] += wv.x * ud;
      acc[eq * 4 + 1] += wv.y * ud;
      acc[eq * 4 + 2] += wv.z * ud;
      acc[eq * 4 + 3] += wv.w * ud;
    }
  }
  float r2 = 0.f;
  #pragma unroll
  for (int e = 0; e < 64; ++e) r2 += acc[e] * acc[e];
  float c = cl[j];
  float s2 = c * c * r2;
  float g = c * s2 / ((1.f + s2) * sqrtf(s2 + FEPS));
  // native row rn = b*512+s ; reference output row R = s*32+b
  int rn = row0 + bl;
  int bb = rn >> 9, s = rn & 511;
  int R = s * 32 + bb;
  float4* op = reinterpret_cast<float4*>(out + ((size_t)j * JB + R) * 64);
  #pragma unroll
  for (int eq = 0; eq < 16; ++eq)
    op[eq] = make_float4(g * acc[eq * 4 + 0], g * acc[eq * 4 + 1],
                         g * acc[eq * 4 + 2], g * acc[eq * 4 + 3]);
}

extern "C" void kernel_launch(void* const* d_in, const int* in_sizes, int n_in,
                              void* d_out, int out_size, void* d_ws, size_t ws_size,
                              hipStream_t stream) {
  const float* x = (const float*)d_in[0];   // (8,32,512,64) f32
  const float* w = (const float*)d_in[1];   // (8,8,64,64)  f32
  float* out = (float*)d_out;               // (8,32,512,64) f32
  float* ws = (float*)d_ws;

  // zero the atomic-accumulator region (ws is poisoned 0xAA before each call)
  hipMemsetAsync(ws, 0, 2048 * sizeof(float), stream);

  k_mean <<<256, 256, 0, stream>>>(x, ws);
  k_uhm  <<<64,  64,  0, stream>>>(w, ws);
  k_r2   <<<512, 256, 0, stream>>>(x, w, ws);
  // routing iter 0 (C = 1/8 exactly since B starts at 0)
  k_t    <<<64,  256, 0, stream>>>(x, ws, nullptr, ws + WS_T0);
  k_bup  <<<1,   512, 0, stream>>>(w, ws, ws + WS_T0, ws + WS_BD0);
  // routing iter 1 (C = softmax(Bd0))
  k_t    <<<64,  256, 0, stream>>>(x, ws, ws + WS_BD0, ws + WS_T1);
  k_bup  <<<1,   512, 0, stream>>>(w, ws, ws + WS_T1, ws + WS_BD1);
  // final v with C = softmax(Bd0+Bd1); 3rd B-update is dead code in the ref
  k_final<<<512, 256, 0, stream>>>(x, w, ws, out);
}

// Round 2
// 177.722 us; speedup vs baseline: 1.5234x; 1.5234x over previous
//
#include <hip/hip_runtime.h>
#include <math.h>

#define NIN  8
#define NOUT 8
#define JB   16384
#define FEPS 1e-9f
#define PADA 65   // A-tile leading-dim pad: bank = (r*65+d)%32 varies with r

// ws float offsets (zero-init region = [0, 2048))
#define WS_UMEAN 0      // 512 floats  : sum over batch of u[i][d]  (atomic)
#define WS_BD0   512    // 64 floats   : B-delta of routing iter 0
#define WS_BD1   576    // 64 floats   : B-delta of routing iter 1
#define WS_T0    1024   // 512 floats  : t[j][d] iter 0 (atomic)
#define WS_T1    1536   // 512 floats  : t[j][d] iter 1 (atomic)
#define WS_UHM   2048   // 4096 floats : u_hat_mean stored as [j][i][e]
#define WS_R2    8192   // 131072 floats: r2[rn][j], rn = b*512+s (x-native)

// ---------------------------------------------------------------- k_mean
// u_mean_sum[i][d] = sum over all (b,s) of x[i][b][s][d]
__global__ __launch_bounds__(256) void k_mean(const float* __restrict__ x,
                                              float* __restrict__ ws) {
  int blk = blockIdx.x;          // 256 blocks: i (8) x chunk (32)
  int i = blk >> 5;
  int c32 = blk & 31;
  int t = threadIdx.x;
  int q = t & 15;                // float4 column 0..15
  int rsub = t >> 4;             // 16 rows in flight
  const float4* xr = reinterpret_cast<const float4*>(x) +
                     (size_t)(i * JB + c32 * 512) * 16;
  float4 a = make_float4(0.f, 0.f, 0.f, 0.f);
  for (int rr = rsub; rr < 512; rr += 16) {
    float4 v = xr[rr * 16 + q];
    a.x += v.x; a.y += v.y; a.z += v.z; a.w += v.w;
  }
  __shared__ float4 s4[256];
  s4[t] = a;
  __syncthreads();
  if (t < 16) {
    float4 s = s4[t];
    for (int k = 1; k < 16; ++k) {
      float4 v = s4[t + k * 16];
      s.x += v.x; s.y += v.y; s.z += v.z; s.w += v.w;
    }
    float* um = ws + WS_UMEAN + i * 64 + q * 4;
    atomicAdd(um + 0, s.x);
    atomicAdd(um + 1, s.y);
    atomicAdd(um + 2, s.z);
    atomicAdd(um + 3, s.w);
  }
}

// ---------------------------------------------------------------- k_uhm
// uhm[j][i][e] = (1/JB) * sum_d weights[i][j][d][e] * u_mean_sum[i][d]
__global__ __launch_bounds__(64) void k_uhm(const float* __restrict__ w,
                                            float* __restrict__ ws) {
  int blk = blockIdx.x;          // 64 blocks: i*8+j
  int i = blk >> 3, j = blk & 7;
  int e = threadIdx.x;
  const float* wij = w + (size_t)((i * 8 + j) * 64) * 64;
  const float* ums = ws + WS_UMEAN + i * 64;
  float acc = 0.f;
  for (int d = 0; d < 64; ++d)
    acc += wij[d * 64 + e] * ums[d];
  ws[WS_UHM + (j * 8 + i) * 64 + e] = acc * (1.0f / (float)JB);
}

// ---------------------------------------------------------------- k_gemm
// p[rn][j][e] = sum_d u7[rn][d] * W7[j][d][e]   (recomputed, never stored)
// MODE 0: write r2[rn][j] = ||p[rn][j][:]||^2
// MODE 1: out[j][R(rn)][e] = g(c_j, r2) * p[rn][j][e]
// Block: 128 rows x 1 j. 256 thr, thread tile 8 rows x 4 cols (32 acc).
template <int MODE>
__global__ __launch_bounds__(256) void k_gemm(const float* __restrict__ x,
                                              const float* __restrict__ w,
                                              float* __restrict__ ws,
                                              float* __restrict__ out) {
  __shared__ float As[128 * PADA];   // 33.3 KB
  __shared__ float Bs[64 * 64];      // 16 KB, d-major
  __shared__ float cj_s;
  int t = threadIdx.x;
  int j = blockIdx.x & 7;
  int rn0 = (blockIdx.x >> 3) * 128;  // 128 row-chunks
  const float* x7 = x + (size_t)7 * JB * 64;

  // stage A: 128x64 contiguous rows, coalesced float4, scalar LDS writes (pad)
  const float4* ag = reinterpret_cast<const float4*>(x7 + (size_t)rn0 * 64);
  #pragma unroll
  for (int k = 0; k < 8; ++k) {
    int f = t + k * 256;             // float4 index 0..2047
    float4 v = ag[f];
    float* dst = As + (f >> 4) * PADA + (f & 15) * 4;
    dst[0] = v.x; dst[1] = v.y; dst[2] = v.z; dst[3] = v.w;
  }
  // stage B: W7[j] 64x64, float4 all the way
  const float4* bg = reinterpret_cast<const float4*>(w + (size_t)((7 * 8 + j) * 64) * 64);
  float4* bs4 = reinterpret_cast<float4*>(Bs);
  #pragma unroll
  for (int k = 0; k < 4; ++k)
    bs4[t + k * 256] = bg[t + k * 256];
  if (MODE == 1 && t == 0) {
    float bv[8]; float m = -1e30f;
    for (int i = 0; i < 8; ++i) {
      bv[i] = ws[WS_BD0 + i * 8 + j] + ws[WS_BD1 + i * 8 + j];
      m = fmaxf(m, bv[i]);
    }
    float ssum = 0.f;
    for (int i = 0; i < 8; ++i) ssum += expf(bv[i] - m);
    cj_s = expf(bv[7] - m) / ssum;
  }
  __syncthreads();

  int tx = t & 15;                   // cols tx*4 .. tx*4+3
  int ty = t >> 4;                   // rows ty*8 .. ty*8+7
  float acc[8][4];
  #pragma unroll
  for (int r = 0; r < 8; ++r)
    #pragma unroll
    for (int c = 0; c < 4; ++c) acc[r][c] = 0.f;

  const float* arow = As + ty * 8 * PADA;
  const float4* b4 = reinterpret_cast<const float4*>(Bs) + tx;
  #pragma unroll 8
  for (int d = 0; d < 64; ++d) {
    float4 wv = b4[d * 16];          // 2-way bank alias: free
    float av[8];
    #pragma unroll
    for (int r = 0; r < 8; ++r) av[r] = arow[r * PADA + d];  // bcast, no conflict
    #pragma unroll
    for (int r = 0; r < 8; ++r) {
      acc[r][0] += av[r] * wv.x;
      acc[r][1] += av[r] * wv.y;
      acc[r][2] += av[r] * wv.z;
      acc[r][3] += av[r] * wv.w;
    }
  }

  // per-row ||.||^2 : 4 local squares, then reduce across the 16 tx lanes
  float r2v[8];
  #pragma unroll
  for (int r = 0; r < 8; ++r) {
    float s = acc[r][0] * acc[r][0] + acc[r][1] * acc[r][1] +
              acc[r][2] * acc[r][2] + acc[r][3] * acc[r][3];
    #pragma unroll
    for (int m = 1; m < 16; m <<= 1)
      s += __shfl_xor(s, m, 64);
    r2v[r] = s;
  }

  if (MODE == 0) {
    if (tx == 0) {
      #pragma unroll
      for (int r = 0; r < 8; ++r)
        ws[WS_R2 + (size_t)(rn0 + ty * 8 + r) * 8 + j] = r2v[r];
    }
  } else {
    float c = cj_s;
    #pragma unroll
    for (int r = 0; r < 8; ++r) {
      float s2 = c * c * r2v[r];
      float g = c * s2 / ((1.f + s2) * sqrtf(s2 + FEPS));
      int rn = rn0 + ty * 8 + r;
      int bb = rn >> 9, sidx = rn & 511;
      int R = sidx * 32 + bb;        // reference jb-row remap
      float4 o = make_float4(g * acc[r][0], g * acc[r][1],
                             g * acc[r][2], g * acc[r][3]);
      // 16 tx lanes cover one full 256B output row -> full-line writes
      reinterpret_cast<float4*>(out + ((size_t)j * JB + R) * 64)[tx] = o;
    }
  }
}

// ---------------------------------------------------------------- k_t
// t[j][d] += sum over 64 rows of g(c_j, r2[rn][j]) * u7[rn][d]
// bsrc == nullptr -> iteration 0, C[7][j] = 1/8 exactly
__global__ __launch_bounds__(256) void k_t(const float* __restrict__ x,
                                           const float* __restrict__ ws,
                                           const float* __restrict__ bsrc,
                                           float* __restrict__ tdst) {
  __shared__ float ut[64][65];
  __shared__ float gl[64][8];
  __shared__ float cl[8];
  int t = threadIdx.x;
  if (t < 8) {
    float c;
    if (bsrc == nullptr) {
      c = 0.125f;
    } else {
      float bv[8]; float m = -1e30f;
      for (int i = 0; i < 8; ++i) { bv[i] = bsrc[i * 8 + t]; m = fmaxf(m, bv[i]); }
      float s = 0.f;
      for (int i = 0; i < 8; ++i) s += expf(bv[i] - m);
      c = expf(bv[7] - m) / s;
    }
    cl[t] = c;
  }
  __syncthreads();
  int rowbase = blockIdx.x * 64;     // 256 blocks x 64 rows
  const float* x7 = x + (size_t)7 * JB * 64;
  const float4* ag = reinterpret_cast<const float4*>(x7 + (size_t)rowbase * 64);
  #pragma unroll
  for (int k = 0; k < 4; ++k) {
    int f = t + k * 256;             // float4 idx 0..1023
    float4 v = ag[f];
    float* dst = &ut[f >> 4][(f & 15) * 4];
    dst[0] = v.x; dst[1] = v.y; dst[2] = v.z; dst[3] = v.w;
  }
  {
    int k2 = t * 2;                  // g for 64 rows x 8 j : 512 values
    int r = k2 >> 3, jj = k2 & 7;
    const float* r2p = ws + WS_R2 + (size_t)rowbase * 8;
    #pragma unroll
    for (int u = 0; u < 2; ++u) {
      float r2v = r2p[r * 8 + jj + u];
      float c = cl[jj + u];
      float s2 = c * c * r2v;
      gl[r][jj + u] = c * s2 / ((1.f + s2) * sqrtf(s2 + FEPS));
    }
  }
  __syncthreads();
  int j = t >> 5, dp = t & 31;
  float a0 = 0.f, a1 = 0.f;
  for (int r = 0; r < 64; ++r) {
    float g = gl[r][j];              // broadcast
    a0 += g * ut[r][2 * dp];         // 2-way bank alias: free
    a1 += g * ut[r][2 * dp + 1];
  }
  atomicAdd(&tdst[j * 64 + 2 * dp], a0);
  atomicAdd(&tdst[j * 64 + 2 * dp + 1], a1);
}

// ---------------------------------------------------------------- k_bup
// v_mean[j][e] = (1/JB) sum_d W7[j][d][e] * t[j][d]
// bdst[i][j]   = sum_e uhm[j][i][e] * v_mean[j][e]
__global__ __launch_bounds__(512) void k_bup(const float* __restrict__ w,
                                             const float* __restrict__ ws,
                                             const float* __restrict__ tsrc,
                                             float* __restrict__ bdst) {
  __shared__ float vm[8][64];
  int t = threadIdx.x;               // 512
  int j = t >> 6, e = t & 63;
  const float* w7j = w + (size_t)((7 * 8 + j) * 64) * 64;
  const float* tj = tsrc + j * 64;
  float acc = 0.f;
  for (int d = 0; d < 64; ++d)
    acc += w7j[d * 64 + e] * tj[d];
  vm[j][e] = acc * (1.0f / (float)JB);
  __syncthreads();
  if (t < 64) {
    int i = t >> 3, jj = t & 7;
    const float* uhm = ws + WS_UHM + (jj * 8 + i) * 64;
    float b = 0.f;
    for (int ee = 0; ee < 64; ++ee)
      b += uhm[ee] * vm[jj][ee];
    bdst[i * 8 + jj] = b;
  }
}

extern "C" void kernel_launch(void* const* d_in, const int* in_sizes, int n_in,
                              void* d_out, int out_size, void* d_ws, size_t ws_size,
                              hipStream_t stream) {
  const float* x = (const float*)d_in[0];   // (8,32,512,64) f32
  const float* w = (const float*)d_in[1];   // (8,8,64,64)  f32
  float* out = (float*)d_out;               // (8,32,512,64) f32
  float* ws = (float*)d_ws;

  hipMemsetAsync(ws, 0, 2048 * sizeof(float), stream);

  k_mean   <<<256,  256, 0, stream>>>(x, ws);
  k_uhm    <<<64,   64,  0, stream>>>(w, ws);
  k_gemm<0><<<1024, 256, 0, stream>>>(x, w, ws, out);   // r2 pass
  // routing iter 0 (C = 1/8 exactly since B starts at 0)
  k_t      <<<256,  256, 0, stream>>>(x, ws, nullptr, ws + WS_T0);
  k_bup    <<<1,    512, 0, stream>>>(w, ws, ws + WS_T0, ws + WS_BD0);
  // routing iter 1 (C = softmax(Bd0))
  k_t      <<<256,  256, 0, stream>>>(x, ws, ws + WS_BD0, ws + WS_T1);
  k_bup    <<<1,    512, 0, stream>>>(w, ws, ws + WS_T1, ws + WS_BD1);
  // final v with C = softmax(Bd0+Bd1); 3rd B-update is dead code in the ref
  k_gemm<1><<<1024, 256, 0, stream>>>(x, w, ws, out);
}

// Round 4
// 159.518 us; speedup vs baseline: 1.6973x; 1.1141x over previous
//
#include <hip/hip_runtime.h>
#include <math.h>

#define NIN  8
#define NOUT 8
#define JB   16384
#define FEPS 1e-9f

// ws float offsets (zero-init region = [0, 2048))
#define WS_UMEAN 0       // 512 floats  : sum over batch of u[i][d]  (atomic)
#define WS_BD0   512     // 64 floats   : B-delta of routing iter 0
#define WS_BD1   576     // 64 floats   : B-delta of routing iter 1
#define WS_T0    1024    // 512 floats  : t[j][d] iter 0 (atomic)
#define WS_T1    1536    // 512 floats  : t[j][d] iter 1 (atomic)
#define WS_UHM   2048    // 4096 floats : u_hat_mean stored as [j][i][e]
#define WS_R2    8192    // 131072 floats: r2[rn][j], rn = b*512+s (x-native)
#define WS_X7B   139264  // 1048576 ushorts (524288 floats): bf16 x7 [rn][d]
#define WS_BT    663552  // 32768 ushorts: Bt[n][k]=bf16(W7[n>>6][k][n&63])
                         // (was 270336 in r3 — overlapped x7b rows 4096..4607!)

typedef short short8 __attribute__((ext_vector_type(8)));
typedef float f32x4  __attribute__((ext_vector_type(4)));

static __device__ inline ushort f2bf(float f) {
  union { float f; unsigned u; } a; a.f = f;
  unsigned u = a.u;
  u += 0x7fffu + ((u >> 16) & 1u);   // RNE
  return (ushort)(u >> 16);
}

// ---------------------------------------------------------------- k_mean
// u_mean_sum[i][d] = sum over (b,s) of x[i][b][s][d]; i==7 also emits bf16 x7
__global__ __launch_bounds__(256) void k_mean(const float* __restrict__ x,
                                              float* __restrict__ ws) {
  int blk = blockIdx.x;          // 256 blocks: i (8) x chunk (32)
  int i = blk >> 5;
  int c32 = blk & 31;
  int t = threadIdx.x;
  int q = t & 15;                // float4 column 0..15
  int rsub = t >> 4;             // 16 rows in flight
  const float4* xr = reinterpret_cast<const float4*>(x) +
                     (size_t)(i * JB + c32 * 512) * 16;
  ushort* x7b = (ushort*)(ws + WS_X7B);
  float4 a = make_float4(0.f, 0.f, 0.f, 0.f);
  for (int rr = rsub; rr < 512; rr += 16) {
    float4 v = xr[rr * 16 + q];
    a.x += v.x; a.y += v.y; a.z += v.z; a.w += v.w;
    if (i == 7) {                // uniform branch
      ushort4 h = make_ushort4(f2bf(v.x), f2bf(v.y), f2bf(v.z), f2bf(v.w));
      *reinterpret_cast<ushort4*>(x7b + (size_t)(c32 * 512 + rr) * 64 + q * 4) = h;
    }
  }
  __shared__ float4 s4[256];
  s4[t] = a;
  __syncthreads();
  if (t < 16) {
    float4 s = s4[t];
    for (int k = 1; k < 16; ++k) {
      float4 v = s4[t + k * 16];
      s.x += v.x; s.y += v.y; s.z += v.z; s.w += v.w;
    }
    float* um = ws + WS_UMEAN + i * 64 + q * 4;
    atomicAdd(um + 0, s.x);
    atomicAdd(um + 1, s.y);
    atomicAdd(um + 2, s.z);
    atomicAdd(um + 3, s.w);
  }
}

// ---------------------------------------------------------------- k_uhm
// uhm[j][i][e] = (1/JB) * sum_d weights[i][j][d][e] * u_mean_sum[i][d]
// also: block (i,j) converts Bt rows n=j*64+e for e in [8i, 8i+8)
__global__ __launch_bounds__(256) void k_uhm(const float* __restrict__ w,
                                             float* __restrict__ ws) {
  int blk = blockIdx.x;          // 64 blocks: i*8+j
  int i = blk >> 3, j = blk & 7;
  int t = threadIdx.x;
  ushort* bt = (ushort*)(ws + WS_BT);
  #pragma unroll
  for (int p = 0; p < 2; ++p) {
    int local = t + p * 256;     // 0..511
    int eo = local >> 6;         // 0..7
    int k = local & 63;
    int e = i * 8 + eo;
    float v = w[(size_t)(56 + j) * 4096 + k * 64 + e];
    bt[(size_t)(j * 64 + e) * 64 + k] = f2bf(v);
  }
  if (t < 64) {
    int e = t;
    const float* wij = w + (size_t)((i * 8 + j) * 64) * 64;
    const float* ums = ws + WS_UMEAN + i * 64;
    float acc = 0.f;
    for (int d = 0; d < 64; ++d)
      acc += wij[d * 64 + e] * ums[d];
    ws[WS_UHM + (j * 8 + i) * 64 + e] = acc * (1.0f / (float)JB);
  }
}

// ---------------------------------------------------------------- k_gemm (MFMA)
// p[row][j*64+e] = sum_d u7bf[row][d] * W7bf[j][d][e]  via 16x16x32 bf16 MFMA
// MODE 0: rows indexed rn (x-native); writes r2[rn][j] = ||p[rn][j][:]||^2
// MODE 1: rows indexed rv (output-native, rv = s*32+b); writes
//         out[j][rv][e] = g(c_j, r2) * p, with r2 recomputed from acc.
// Block: 4 waves, 128 rows x 64 cols (one j). Grid 1024 = 128 x 8.
template <int MODE>
__global__ __launch_bounds__(256) void k_gemm(const ushort* __restrict__ x7b,
                                              const ushort* __restrict__ bt,
                                              float* __restrict__ ws,
                                              float* __restrict__ out) {
  int t = threadIdx.x;
  int lane = t & 63, wv = t >> 6;
  int j = blockIdx.x & 7;
  int rm0 = (blockIdx.x >> 3) * 128;
  int m = lane & 15, quad = lane >> 4;

  // B fragments: 4 n-tiles x 2 k-halves; B[k][n], lane holds n=m, k=quad*8+..
  short8 bfr[4][2];
  const ushort* btj = bt + (size_t)(j * 64) * 64;
  #pragma unroll
  for (int nt = 0; nt < 4; ++nt)
    #pragma unroll
    for (int kb = 0; kb < 2; ++kb)
      bfr[nt][kb] = *reinterpret_cast<const short8*>(
          btj + (size_t)(nt * 16 + m) * 64 + kb * 32 + quad * 8);

  float cj = 0.f;
  if (MODE == 1) {
    float bv[8]; float mx = -1e30f;
    #pragma unroll
    for (int i = 0; i < 8; ++i) {
      bv[i] = ws[WS_BD0 + i * 8 + j] + ws[WS_BD1 + i * 8 + j];
      mx = fmaxf(mx, bv[i]);
    }
    float ssum = 0.f;
    #pragma unroll
    for (int i = 0; i < 8; ++i) ssum += expf(bv[i] - mx);
    cj = expf(bv[7] - mx) / ssum;
  }

  #pragma unroll
  for (int s = 0; s < 2; ++s) {
    int rb = rm0 + s * 64 + wv * 16;        // 16-row strip base
    // A fragments: lane holds row m, k=quad*8+..
    const ushort* ap;
    if (MODE == 0) {
      ap = x7b + (size_t)(rb + m) * 64 + quad * 8;
    } else {
      int rv = rb + m;
      int rn = ((rv & 31) << 9) | (rv >> 5); // rn = b*512 + s_idx
      ap = x7b + (size_t)rn * 64 + quad * 8;
    }
    short8 a0 = *reinterpret_cast<const short8*>(ap);
    short8 a1 = *reinterpret_cast<const short8*>(ap + 32);

    f32x4 acc[4];
    #pragma unroll
    for (int nt = 0; nt < 4; ++nt) acc[nt] = (f32x4){0.f, 0.f, 0.f, 0.f};
    #pragma unroll
    for (int nt = 0; nt < 4; ++nt) {
      acc[nt] = __builtin_amdgcn_mfma_f32_16x16x32_bf16(a0, bfr[nt][0], acc[nt], 0, 0, 0);
      acc[nt] = __builtin_amdgcn_mfma_f32_16x16x32_bf16(a1, bfr[nt][1], acc[nt], 0, 0, 0);
    }

    // r2 per row: row = quad*4 + reg, col = m. Reduce squares over 16 lanes.
    float sq[4];
    #pragma unroll
    for (int r = 0; r < 4; ++r)
      sq[r] = acc[0][r] * acc[0][r] + acc[1][r] * acc[1][r] +
              acc[2][r] * acc[2][r] + acc[3][r] * acc[3][r];
    #pragma unroll
    for (int mk = 1; mk < 16; mk <<= 1) {
      #pragma unroll
      for (int r = 0; r < 4; ++r)
        sq[r] += __shfl_xor(sq[r], mk, 64);
    }

    if (MODE == 0) {
      if (m == 0) {
        #pragma unroll
        for (int r = 0; r < 4; ++r)
          ws[WS_R2 + (size_t)(rb + quad * 4 + r) * 8 + j] = sq[r];
      }
    } else {
      #pragma unroll
      for (int r = 0; r < 4; ++r) {
        float s2 = cj * cj * sq[r];
        float g = cj * s2 / ((1.f + s2) * sqrtf(s2 + FEPS));
        size_t base = ((size_t)j * JB + (rb + quad * 4 + r)) * 64;
        #pragma unroll
        for (int nt = 0; nt < 4; ++nt)
          out[base + nt * 16 + m] = g * acc[nt][r];
      }
    }
  }
}

// ---------------------------------------------------------------- k_t
// t[j][d] += sum over 64 rows of g(c_j, r2[rn][j]) * u7[rn][d]  (fp32)
__global__ __launch_bounds__(256) void k_t(const float* __restrict__ x,
                                           const float* __restrict__ ws,
                                           const float* __restrict__ bsrc,
                                           float* __restrict__ tdst) {
  __shared__ float ut[64][65];
  __shared__ float gl[64][8];
  __shared__ float cl[8];
  int t = threadIdx.x;
  if (t < 8) {
    float c;
    if (bsrc == nullptr) {
      c = 0.125f;
    } else {
      float bv[8]; float m = -1e30f;
      for (int i = 0; i < 8; ++i) { bv[i] = bsrc[i * 8 + t]; m = fmaxf(m, bv[i]); }
      float s = 0.f;
      for (int i = 0; i < 8; ++i) s += expf(bv[i] - m);
      c = expf(bv[7] - m) / s;
    }
    cl[t] = c;
  }
  __syncthreads();
  int rowbase = blockIdx.x * 64;     // 256 blocks x 64 rows
  const float* x7 = x + (size_t)7 * JB * 64;
  const float4* ag = reinterpret_cast<const float4*>(x7 + (size_t)rowbase * 64);
  #pragma unroll
  for (int k = 0; k < 4; ++k) {
    int f = t + k * 256;             // float4 idx 0..1023
    float4 v = ag[f];
    float* dst = &ut[f >> 4][(f & 15) * 4];
    dst[0] = v.x; dst[1] = v.y; dst[2] = v.z; dst[3] = v.w;
  }
  {
    int k2 = t * 2;                  // g for 64 rows x 8 j : 512 values
    int r = k2 >> 3, jj = k2 & 7;
    const float* r2p = ws + WS_R2 + (size_t)rowbase * 8;
    #pragma unroll
    for (int u = 0; u < 2; ++u) {
      float r2v = r2p[r * 8 + jj + u];
      float c = cl[jj + u];
      float s2 = c * c * r2v;
      gl[r][jj + u] = c * s2 / ((1.f + s2) * sqrtf(s2 + FEPS));
    }
  }
  __syncthreads();
  int j = t >> 5, dp = t & 31;
  float a0 = 0.f, a1 = 0.f;
  for (int r = 0; r < 64; ++r) {
    float g = gl[r][j];              // broadcast
    a0 += g * ut[r][2 * dp];         // 2-way bank alias: free
    a1 += g * ut[r][2 * dp + 1];
  }
  atomicAdd(&tdst[j * 64 + 2 * dp], a0);
  atomicAdd(&tdst[j * 64 + 2 * dp + 1], a1);
}

// ---------------------------------------------------------------- k_bup
// v_mean[j][e] = (1/JB) sum_d W7[j][d][e] * t[j][d]
// bdst[i][j]   = sum_e uhm[j][i][e] * v_mean[j][e]
__global__ __launch_bounds__(512) void k_bup(const float* __restrict__ w,
                                             const float* __restrict__ ws,
                                             const float* __restrict__ tsrc,
                                             float* __restrict__ bdst) {
  __shared__ float vm[8][64];
  int t = threadIdx.x;               // 512
  int j = t >> 6, e = t & 63;
  const float* w7j = w + (size_t)((7 * 8 + j) * 64) * 64;
  const float* tj = tsrc + j * 64;
  float acc = 0.f;
  for (int d = 0; d < 64; ++d)
    acc += w7j[d * 64 + e] * tj[d];
  vm[j][e] = acc * (1.0f / (float)JB);
  __syncthreads();
  if (t < 64) {
    int i = t >> 3, jj = t & 7;
    const float* uhm = ws + WS_UHM + (jj * 8 + i) * 64;
    float b = 0.f;
    for (int ee = 0; ee < 64; ++ee)
      b += uhm[ee] * vm[jj][ee];
    bdst[i * 8 + jj] = b;
  }
}

extern "C" void kernel_launch(void* const* d_in, const int* in_sizes, int n_in,
                              void* d_out, int out_size, void* d_ws, size_t ws_size,
                              hipStream_t stream) {
  const float* x = (const float*)d_in[0];   // (8,32,512,64) f32
  const float* w = (const float*)d_in[1];   // (8,8,64,64)  f32
  float* out = (float*)d_out;               // (8,32,512,64) f32
  float* ws = (float*)d_ws;
  const ushort* x7b = (const ushort*)(ws + WS_X7B);
  const ushort* bt  = (const ushort*)(ws + WS_BT);

  hipMemsetAsync(ws, 0, 2048 * sizeof(float), stream);

  k_mean   <<<256,  256, 0, stream>>>(x, ws);           // + bf16 x7 copy
  k_uhm    <<<64,   256, 0, stream>>>(w, ws);           // + bf16 Bt transpose
  k_gemm<0><<<1024, 256, 0, stream>>>(x7b, bt, ws, out);  // r2 pass (MFMA)
  // routing iter 0 (C = 1/8 exactly since B starts at 0)
  k_t      <<<256,  256, 0, stream>>>(x, ws, nullptr, ws + WS_T0);
  k_bup    <<<1,    512, 0, stream>>>(w, ws, ws + WS_T0, ws + WS_BD0);
  // routing iter 1 (C = softmax(Bd0))
  k_t      <<<256,  256, 0, stream>>>(x, ws, ws + WS_BD0, ws + WS_T1);
  k_bup    <<<1,    512, 0, stream>>>(w, ws, ws + WS_T1, ws + WS_BD1);
  // final v with C = softmax(Bd0+Bd1); 3rd B-update is dead code in the ref
  k_gemm<1><<<1024, 256, 0, stream>>>(x7b, bt, ws, out);
}

// Round 5
// 152.408 us; speedup vs baseline: 1.7764x; 1.0467x over previous
//
#include <hip/hip_runtime.h>
#include <math.h>

#define NIN  8
#define NOUT 8
#define JB   16384
#define FEPS 1e-9f

// ws float offsets — every region fully written before read: NO memset needed
#define WS_BD0   512     // 64: B-delta iter 0
#define WS_BD1   576     // 64: B-delta iter 1
#define WS_UHM   2048    // 4096: u_hat_mean [j][i][e]
#define WS_R2    8192    // 131072: r2[rn][j], rn = b*512+s (x-native)
#define WS_X7B   139264  // 524288 floats (1M ushorts): bf16 x7 [rn][d]
#define WS_BT    663552  // 16384 floats (32768 ushorts): Bt[n][k]
#define WS_TP0   679936  // 65536: k_t iter0 partials [128 blk][512]
#define WS_TP1   745472  // 65536: k_t iter1 partials
#define WS_UMP   811008  // 16384: u_mean partials [i*32+chunk][64]

typedef short short8 __attribute__((ext_vector_type(8)));
typedef float f32x4  __attribute__((ext_vector_type(4)));

static __device__ inline ushort f2bf(float f) {
  union { float f; unsigned u; } a; a.f = f;
  unsigned u = a.u;
  u += 0x7fffu + ((u >> 16) & 1u);   // RNE
  return (ushort)(u >> 16);
}

// ---------------------------------------------------------------- k_mean
// u-mean partials per (i,chunk); i==7 also emits bf16 x7. No atomics.
__global__ __launch_bounds__(256) void k_mean(const float* __restrict__ x,
                                              float* __restrict__ ws) {
  int blk = blockIdx.x;          // 256 blocks: i (8) x chunk (32)
  int i = blk >> 5;
  int c32 = blk & 31;
  int t = threadIdx.x;
  int q = t & 15;                // float4 column 0..15
  int rsub = t >> 4;             // 16 rows in flight
  const float4* xr = reinterpret_cast<const float4*>(x) +
                     (size_t)(i * JB + c32 * 512) * 16;
  ushort* x7b = (ushort*)(ws + WS_X7B);
  float4 a = make_float4(0.f, 0.f, 0.f, 0.f);
  for (int rr = rsub; rr < 512; rr += 16) {
    float4 v = xr[rr * 16 + q];
    a.x += v.x; a.y += v.y; a.z += v.z; a.w += v.w;
    if (i == 7) {                // uniform branch
      ushort4 h = make_ushort4(f2bf(v.x), f2bf(v.y), f2bf(v.z), f2bf(v.w));
      *reinterpret_cast<ushort4*>(x7b + (size_t)(c32 * 512 + rr) * 64 + q * 4) = h;
    }
  }
  __shared__ float4 s4[256];
  s4[t] = a;
  __syncthreads();
  if (t < 16) {
    float4 s = s4[t];
    for (int k = 1; k < 16; ++k) {
      float4 v = s4[t + k * 16];
      s.x += v.x; s.y += v.y; s.z += v.z; s.w += v.w;
    }
    reinterpret_cast<float4*>(ws + WS_UMP + (size_t)blk * 64)[t] = s;
  }
}

// ---------------------------------------------------------------- k_uhm
// reduce u-mean partials; uhm[j][i][e] = (1/JB) sum_d W[i][j][d][e] um[i][d]
// also: block (i,j) converts Bt rows n=j*64+e for e in [8i, 8i+8)
__global__ __launch_bounds__(256) void k_uhm(const float* __restrict__ w,
                                             float* __restrict__ ws) {
  int blk = blockIdx.x;          // 64 blocks: i*8+j
  int i = blk >> 3, j = blk & 7;
  int t = threadIdx.x;
  ushort* bt = (ushort*)(ws + WS_BT);
  #pragma unroll
  for (int p = 0; p < 2; ++p) {
    int local = t + p * 256;     // 0..511
    int eo = local >> 6;         // 0..7
    int k = local & 63;
    int e = i * 8 + eo;
    float v = w[(size_t)(56 + j) * 4096 + k * 64 + e];
    bt[(size_t)(j * 64 + e) * 64 + k] = f2bf(v);
  }
  __shared__ float ums[64];
  if (t < 64) {
    const float* up = ws + WS_UMP + (size_t)(i * 32) * 64 + t;
    float s = 0.f;
    #pragma unroll 8
    for (int c = 0; c < 32; ++c) s += up[c * 64];
    ums[t] = s;
  }
  __syncthreads();
  if (t < 64) {
    int e = t;
    const float* wij = w + (size_t)((i * 8 + j) * 64) * 64;
    float acc = 0.f;
    for (int d = 0; d < 64; ++d)
      acc += wij[d * 64 + e] * ums[d];
    ws[WS_UHM + (j * 8 + i) * 64 + e] = acc * (1.0f / (float)JB);
  }
}

// ---------------------------------------------------------------- k_gemm (MFMA)
// p[row][j*64+e] = sum_d u7bf[row][d] * W7bf[j][d][e]  via 16x16x32 bf16 MFMA
// MODE 0: rows rn-order; writes r2[rn][j] = ||p||^2
// MODE 1: rows rv-order (rv = s*32+b); out[j][rv][e] = g(c_j, r2) * p
template <int MODE>
__global__ __launch_bounds__(256) void k_gemm(const ushort* __restrict__ x7b,
                                              const ushort* __restrict__ bt,
                                              float* __restrict__ ws,
                                              float* __restrict__ out) {
  int t = threadIdx.x;
  int lane = t & 63, wv = t >> 6;
  int j = blockIdx.x & 7;
  int rm0 = (blockIdx.x >> 3) * 128;
  int m = lane & 15, quad = lane >> 4;

  // B fragments: 4 n-tiles x 2 k-halves; lane holds n=m, k=quad*8+..
  short8 bfr[4][2];
  const ushort* btj = bt + (size_t)(j * 64) * 64;
  #pragma unroll
  for (int nt = 0; nt < 4; ++nt)
    #pragma unroll
    for (int kb = 0; kb < 2; ++kb)
      bfr[nt][kb] = *reinterpret_cast<const short8*>(
          btj + (size_t)(nt * 16 + m) * 64 + kb * 32 + quad * 8);

  float cj = 0.f;
  if (MODE == 1) {
    float bv[8]; float mx = -1e30f;
    #pragma unroll
    for (int i = 0; i < 8; ++i) {
      bv[i] = ws[WS_BD0 + i * 8 + j] + ws[WS_BD1 + i * 8 + j];
      mx = fmaxf(mx, bv[i]);
    }
    float ssum = 0.f;
    #pragma unroll
    for (int i = 0; i < 8; ++i) ssum += expf(bv[i] - mx);
    cj = expf(bv[7] - mx) / ssum;
  }

  #pragma unroll
  for (int s = 0; s < 2; ++s) {
    int rb = rm0 + s * 64 + wv * 16;        // 16-row strip base
    const ushort* ap;
    if (MODE == 0) {
      ap = x7b + (size_t)(rb + m) * 64 + quad * 8;
    } else {
      int rv = rb + m;
      int rn = ((rv & 31) << 9) | (rv >> 5); // rn = b*512 + s_idx
      ap = x7b + (size_t)rn * 64 + quad * 8;
    }
    short8 a0 = *reinterpret_cast<const short8*>(ap);
    short8 a1 = *reinterpret_cast<const short8*>(ap + 32);

    f32x4 acc[4];
    #pragma unroll
    for (int nt = 0; nt < 4; ++nt) acc[nt] = (f32x4){0.f, 0.f, 0.f, 0.f};
    #pragma unroll
    for (int nt = 0; nt < 4; ++nt) {
      acc[nt] = __builtin_amdgcn_mfma_f32_16x16x32_bf16(a0, bfr[nt][0], acc[nt], 0, 0, 0);
      acc[nt] = __builtin_amdgcn_mfma_f32_16x16x32_bf16(a1, bfr[nt][1], acc[nt], 0, 0, 0);
    }

    // r2 per row: row = quad*4 + reg, col = m. Reduce squares over 16 lanes.
    float sq[4];
    #pragma unroll
    for (int r = 0; r < 4; ++r)
      sq[r] = acc[0][r] * acc[0][r] + acc[1][r] * acc[1][r] +
              acc[2][r] * acc[2][r] + acc[3][r] * acc[3][r];
    #pragma unroll
    for (int mk = 1; mk < 16; mk <<= 1) {
      #pragma unroll
      for (int r = 0; r < 4; ++r)
        sq[r] += __shfl_xor(sq[r], mk, 64);
    }

    if (MODE == 0) {
      if (m == 0) {
        #pragma unroll
        for (int r = 0; r < 4; ++r)
          ws[WS_R2 + (size_t)(rb + quad * 4 + r) * 8 + j] = sq[r];
      }
    } else {
      #pragma unroll
      for (int r = 0; r < 4; ++r) {
        float s2 = cj * cj * sq[r];
        float g = cj * s2 / ((1.f + s2) * sqrtf(s2 + FEPS));
        size_t base = ((size_t)j * JB + (rb + quad * 4 + r)) * 64;
        #pragma unroll
        for (int nt = 0; nt < 4; ++nt)
          out[base + nt * 16 + m] = g * acc[nt][r];
      }
    }
  }
}

// ---------------------------------------------------------------- k_t
// partial[blk][j*64+d] = sum over this block's 128 rows of g * u7[rn][d]
// NO global atomics. bsrc == nullptr -> iter 0, C[7][j] = 1/8 exactly.
__global__ __launch_bounds__(256) void k_t(const float* __restrict__ x,
                                           const float* __restrict__ ws,
                                           const float* __restrict__ bsrc,
                                           float* __restrict__ tp) {
  __shared__ float ut[64][65];
  __shared__ float gl[64][8];
  __shared__ float cl[8];
  int t = threadIdx.x;
  if (t < 8) {
    float c;
    if (bsrc == nullptr) {
      c = 0.125f;
    } else {
      float bv[8]; float m = -1e30f;
      for (int i = 0; i < 8; ++i) { bv[i] = bsrc[i * 8 + t]; m = fmaxf(m, bv[i]); }
      float s = 0.f;
      for (int i = 0; i < 8; ++i) s += expf(bv[i] - m);
      c = expf(bv[7] - m) / s;
    }
    cl[t] = c;
  }
  __syncthreads();
  int j = t >> 5, dp = t & 31;
  float a0 = 0.f, a1 = 0.f;
  const float* x7 = x + (size_t)7 * JB * 64;
  for (int st = 0; st < 2; ++st) {           // 128 blocks x 2 tiles of 64 rows
    int rowbase = blockIdx.x * 128 + st * 64;
    const float4* ag = reinterpret_cast<const float4*>(x7 + (size_t)rowbase * 64);
    #pragma unroll
    for (int k = 0; k < 4; ++k) {
      int f = t + k * 256;                   // float4 idx 0..1023
      float4 v = ag[f];
      float* dst = &ut[f >> 4][(f & 15) * 4];
      dst[0] = v.x; dst[1] = v.y; dst[2] = v.z; dst[3] = v.w;
    }
    {
      int k2 = t * 2;                        // g for 64 rows x 8 j
      int r = k2 >> 3, jj = k2 & 7;
      const float* r2p = ws + WS_R2 + (size_t)rowbase * 8;
      #pragma unroll
      for (int u = 0; u < 2; ++u) {
        float r2v = r2p[r * 8 + jj + u];
        float c = cl[jj + u];
        float s2 = c * c * r2v;
        gl[r][jj + u] = c * s2 / ((1.f + s2) * sqrtf(s2 + FEPS));
      }
    }
    __syncthreads();
    for (int r = 0; r < 64; ++r) {
      float g = gl[r][j];                    // broadcast
      a0 += g * ut[r][2 * dp];               // 2-way bank alias: free
      a1 += g * ut[r][2 * dp + 1];
    }
    __syncthreads();
  }
  tp[(size_t)blockIdx.x * 512 + j * 64 + 2 * dp]     = a0;
  tp[(size_t)blockIdx.x * 512 + j * 64 + 2 * dp + 1] = a1;
}

// ---------------------------------------------------------------- k_bup
// reduce 128 k_t partials -> t[j][d]; vm[j][e] = (1/JB) sum_d W7[j][d][e] t;
// bdst[i][j] = sum_e uhm[j][i][e] * vm[j][e]
__global__ __launch_bounds__(512) void k_bup(const float* __restrict__ w,
                                             const float* __restrict__ ws,
                                             const float* __restrict__ tp,
                                             float* __restrict__ bdst) {
  __shared__ float tl[512];
  __shared__ float vm[8][64];
  int t = threadIdx.x;               // 512
  {
    float s = 0.f;
    #pragma unroll 8
    for (int b = 0; b < 128; ++b) s += tp[(size_t)b * 512 + t];
    tl[t] = s;
  }
  __syncthreads();
  int j = t >> 6, e = t & 63;
  const float* w7j = w + (size_t)((7 * 8 + j) * 64) * 64;
  float acc = 0.f;
  for (int d = 0; d < 64; ++d)
    acc += w7j[d * 64 + e] * tl[j * 64 + d];
  vm[j][e] = acc * (1.0f / (float)JB);
  __syncthreads();
  if (t < 64) {
    int i = t >> 3, jj = t & 7;
    const float* uhm = ws + WS_UHM + (jj * 8 + i) * 64;
    float b = 0.f;
    for (int ee = 0; ee < 64; ++ee)
      b += uhm[ee] * vm[jj][ee];
    bdst[i * 8 + jj] = b;
  }
}

extern "C" void kernel_launch(void* const* d_in, const int* in_sizes, int n_in,
                              void* d_out, int out_size, void* d_ws, size_t ws_size,
                              hipStream_t stream) {
  const float* x = (const float*)d_in[0];   // (8,32,512,64) f32
  const float* w = (const float*)d_in[1];   // (8,8,64,64)  f32
  float* out = (float*)d_out;               // (8,32,512,64) f32
  float* ws = (float*)d_ws;
  const ushort* x7b = (const ushort*)(ws + WS_X7B);
  const ushort* bt  = (const ushort*)(ws + WS_BT);

  // no memset: every ws region is fully written before it is read
  k_mean   <<<256,  256, 0, stream>>>(x, ws);           // + bf16 x7 copy
  k_uhm    <<<64,   256, 0, stream>>>(w, ws);           // + bf16 Bt transpose
  k_gemm<0><<<1024, 256, 0, stream>>>(x7b, bt, ws, out);  // r2 pass (MFMA)
  // routing iter 0 (C = 1/8 exactly since B starts at 0)
  k_t      <<<128,  256, 0, stream>>>(x, ws, nullptr, ws + WS_TP0);
  k_bup    <<<1,    512, 0, stream>>>(w, ws, ws + WS_TP0, ws + WS_BD0);
  // routing iter 1 (C = softmax(Bd0))
  k_t      <<<128,  256, 0, stream>>>(x, ws, ws + WS_BD0, ws + WS_TP1);
  k_bup    <<<1,    512, 0, stream>>>(w, ws, ws + WS_TP1, ws + WS_BD1);
  // final v with C = softmax(Bd0+Bd1); 3rd B-update is dead code in the ref
  k_gemm<1><<<1024, 256, 0, stream>>>(x7b, bt, ws, out);
}